// Round 3
// baseline (793.422 us; speedup 1.0000x reference)
//
#include <hip/hip_runtime.h>
#include <cstddef>

// SelfAttention_71571335020783 on MI355X (gfx950)
constexpr int E     = 2048;
constexpr int SEQ   = 2048;
constexpr int BATCH = 2;
constexpr int BS    = BATCH * SEQ;   // 4096

constexpr int BM = 128, BN = 128, BK = 32;

typedef __bf16 bf16x4 __attribute__((ext_vector_type(4)));
typedef __bf16 bf16x8 __attribute__((ext_vector_type(8)));
typedef float  f32x4  __attribute__((ext_vector_type(4)));

// Byte offset into a [128 rows][32 k] bf16 LDS tile (64B rows), with a
// chunk-XOR swizzle: 16B k-chunk index is XOR'd with row bits so the
// fragment ds_read_b128 (lanes 0-15 = consecutive rows, fixed chunk) hits
// distinct bank-quads (2-way per 16-lane group = free).
__device__ __forceinline__ int lds_off(int row, int kbyte) {
    int chunk  = (kbyte >> 4) ^ ((row >> 1) & 3);
    int within = kbyte & 15;
    return row * 64 + chunk * 16 + within;
}

// Stage a 128x32 fp32 tile whose k-dim is contiguous in global memory:
// element (row, k) at g[(row0+row)*ld + k0 + k]. Writes bf16 hi (and lo).
template <int NT>
__device__ __forceinline__ void stage_direct(
    const float* __restrict__ g, int ld, int row0, int k0,
    char* ldsH, char* ldsL, int tid)
{
    const int kq = tid & 7;    // float4 index along k (k = kq*4)
    const int r0 = tid >> 3;   // 0..31
#pragma unroll
    for (int p = 0; p < 4; ++p) {
        const int row = r0 + p * 32;
        const float4 v = *reinterpret_cast<const float4*>(
            &g[(size_t)(row0 + row) * ld + (k0 + kq * 4)]);
        __bf16 h0 = (__bf16)v.x, h1 = (__bf16)v.y, h2 = (__bf16)v.z, h3 = (__bf16)v.w;
        bf16x4 hv = {h0, h1, h2, h3};
        *reinterpret_cast<bf16x4*>(ldsH + lds_off(row, kq * 8)) = hv;
        if (NT == 2) {
            bf16x4 lv = {(__bf16)(v.x - (float)h0), (__bf16)(v.y - (float)h1),
                         (__bf16)(v.z - (float)h2), (__bf16)(v.w - (float)h3)};
            *reinterpret_cast<bf16x4*>(ldsL + lds_off(row, kq * 8)) = lv;
        }
    }
}

// Stage with transpose: global element (k, d) at g[(k0+k)*ld + d0 + d],
// contiguous in d. LDS row = d, k-byte = 2k.
template <int NT>
__device__ __forceinline__ void stage_transpose(
    const float* __restrict__ g, int ld, int d0, int k0,
    char* ldsH, char* ldsL, int tid)
{
    const int kb = tid & 7;    // k within pass
    const int dq = tid >> 3;   // d = dq*4
#pragma unroll
    for (int p = 0; p < 4; ++p) {
        const int kk = kb + p * 8;
        const float4 v = *reinterpret_cast<const float4*>(
            &g[(size_t)(k0 + kk) * ld + (d0 + dq * 4)]);
        float f[4] = {v.x, v.y, v.z, v.w};
#pragma unroll
        for (int j = 0; j < 4; ++j) {
            __bf16 h = (__bf16)f[j];
            *reinterpret_cast<__bf16*>(ldsH + lds_off(dq * 4 + j, kk * 2)) = h;
            if (NT == 2) {
                __bf16 l = (__bf16)(f[j] - (float)h);
                *reinterpret_cast<__bf16*>(ldsL + lds_off(dq * 4 + j, kk * 2)) = l;
            }
        }
    }
}

// C[m,n] = alpha * sum_k opA[m,k] * opB[k,n]
//   AMODE 0: A[m,k] at A[m*lda+k]      AMODE 1: A[k,m] at A[k*lda+m]
//   BMODE 0: B[k,n] at B[k*ldb+n]      BMODE 1: B[n,k] at B[n*ldb+k]
// NT==2: hi/lo compensated (3 MFMA products, ~fp32 accuracy).
template <int AMODE, int BMODE, int NT>
__global__ __launch_bounds__(256) void gemm_mfma(
    const float* __restrict__ A, const float* __restrict__ B,
    float* __restrict__ C, int K, int lda, int ldb, int ldc,
    long long strideA, long long strideB, long long strideC, float alpha)
{
    alignas(16) __shared__ char AhL[BM * 64];
    alignas(16) __shared__ char BhL[BN * 64];
    alignas(16) __shared__ char AlL[(NT == 2) ? BM * 64 : 16];
    alignas(16) __shared__ char BlL[(NT == 2) ? BN * 64 : 16];

    const int tid = threadIdx.x;
    const int l   = tid & 63;
    const int w   = tid >> 6;          // wave 0..3
    const int wm  = (w >> 1) * 64;     // wave row offset in tile
    const int wn  = (w & 1) * 64;      // wave col offset in tile
    const int m0  = blockIdx.y * BM;
    const int n0  = blockIdx.x * BN;

    const float* Ab = A + (size_t)blockIdx.z * strideA;
    const float* Bb = B + (size_t)blockIdx.z * strideB;
    float*       Cb = C + (size_t)blockIdx.z * strideC;

    f32x4 acc[4][4];
    const f32x4 zero = {0.f, 0.f, 0.f, 0.f};
#pragma unroll
    for (int i = 0; i < 4; ++i)
#pragma unroll
        for (int j = 0; j < 4; ++j) acc[i][j] = zero;

    const int lrow = l & 15;           // fragment row/col within 16
    const int kch  = (l >> 4) * 16;    // k-chunk byte for this lane group

    for (int k0 = 0; k0 < K; k0 += BK) {
        if (AMODE == 0) stage_direct<NT>(Ab, lda, m0, k0, AhL, AlL, tid);
        else            stage_transpose<NT>(Ab, lda, m0, k0, AhL, AlL, tid);
        if (BMODE == 0) stage_transpose<NT>(Bb, ldb, n0, k0, BhL, BlL, tid);
        else            stage_direct<NT>(Bb, ldb, n0, k0, BhL, BlL, tid);
        __syncthreads();

        bf16x8 ah[4], bh[4], al[4], bl[4];
#pragma unroll
        for (int i = 0; i < 4; ++i) {
            ah[i] = *reinterpret_cast<const bf16x8*>(AhL + lds_off(wm + i * 16 + lrow, kch));
            bh[i] = *reinterpret_cast<const bf16x8*>(BhL + lds_off(wn + i * 16 + lrow, kch));
            if (NT == 2) {
                al[i] = *reinterpret_cast<const bf16x8*>(AlL + lds_off(wm + i * 16 + lrow, kch));
                bl[i] = *reinterpret_cast<const bf16x8*>(BlL + lds_off(wn + i * 16 + lrow, kch));
            }
        }
#pragma unroll
        for (int i = 0; i < 4; ++i)
#pragma unroll
            for (int j = 0; j < 4; ++j) {
                acc[i][j] = __builtin_amdgcn_mfma_f32_16x16x32_bf16(ah[i], bh[j], acc[i][j], 0, 0, 0);
                if (NT == 2) {
                    acc[i][j] = __builtin_amdgcn_mfma_f32_16x16x32_bf16(ah[i], bl[j], acc[i][j], 0, 0, 0);
                    acc[i][j] = __builtin_amdgcn_mfma_f32_16x16x32_bf16(al[i], bh[j], acc[i][j], 0, 0, 0);
                }
            }
        __syncthreads();
    }

    // Epilogue. C/D layout (HW-verified m89/m91): col = lane&15, row = (lane>>4)*4 + r.
#pragma unroll
    for (int i = 0; i < 4; ++i)
#pragma unroll
        for (int j = 0; j < 4; ++j) {
#pragma unroll
            for (int r = 0; r < 4; ++r) {
                const int row = m0 + wm + i * 16 + (l >> 4) * 4 + r;
                const int col = n0 + wn + j * 16 + lrow;
                Cb[(size_t)row * ldc + col] = alpha * acc[i][j][r];
            }
        }
}

// Row softmax over 2048-wide rows, in place (fp32). One 256-thread block/row.
__global__ __launch_bounds__(256) void softmax_rows(float* __restrict__ S)
{
    float* row = S + (size_t)blockIdx.x * 2048;
    const int tid = threadIdx.x;

    float4 v0 = reinterpret_cast<const float4*>(row)[tid];
    float4 v1 = reinterpret_cast<const float4*>(row)[tid + 256];

    float m = fmaxf(fmaxf(fmaxf(v0.x, v0.y), fmaxf(v0.z, v0.w)),
                    fmaxf(fmaxf(v1.x, v1.y), fmaxf(v1.z, v1.w)));
#pragma unroll
    for (int off = 32; off > 0; off >>= 1) m = fmaxf(m, __shfl_xor(m, off));

    __shared__ float red[8];
    if ((tid & 63) == 0) red[tid >> 6] = m;
    __syncthreads();
    m = fmaxf(fmaxf(red[0], red[1]), fmaxf(red[2], red[3]));

    v0.x = __expf(v0.x - m); v0.y = __expf(v0.y - m);
    v0.z = __expf(v0.z - m); v0.w = __expf(v0.w - m);
    v1.x = __expf(v1.x - m); v1.y = __expf(v1.y - m);
    v1.z = __expf(v1.z - m); v1.w = __expf(v1.w - m);

    float s = v0.x + v0.y + v0.z + v0.w + v1.x + v1.y + v1.z + v1.w;
#pragma unroll
    for (int off = 32; off > 0; off >>= 1) s += __shfl_xor(s, off);
    if ((tid & 63) == 0) red[4 + (tid >> 6)] = s;
    __syncthreads();
    s = red[4] + red[5] + red[6] + red[7];

    const float inv = 1.0f / s;
    v0.x *= inv; v0.y *= inv; v0.z *= inv; v0.w *= inv;
    v1.x *= inv; v1.y *= inv; v1.z *= inv; v1.w *= inv;
    reinterpret_cast<float4*>(row)[tid]       = v0;
    reinterpret_cast<float4*>(row)[tid + 256] = v1;
}

extern "C" void kernel_launch(void* const* d_in, const int* in_sizes, int n_in,
                              void* d_out, int out_size, void* d_ws, size_t ws_size,
                              hipStream_t stream)
{
    const float* x  = (const float*)d_in[0];  // [2,2048,2048] == [4096,2048]
    const float* Wq = (const float*)d_in[1];
    const float* Wk = (const float*)d_in[2];
    const float* Wv = (const float*)d_in[3];
    const float* Wo = (const float*)d_in[4];
    float* out = (float*)d_out;               // [4096,2048] fp32

    // ws (fp32): Q | K | V | S   (AO overwrites Q). 128 MiB total.
    float* ws = (float*)d_ws;
    const size_t MAT  = (size_t)BS * E;       // 8,388,608
    const long long BMAT = (long long)E * E;  // per-batch 2048x2048
    float* Q  = ws;
    float* Km = ws + MAT;
    float* V  = ws + 2 * MAT;
    float* S  = ws + 3 * MAT;

    const dim3 blk(256);
    const dim3 gBig(E / BN, BS / BM, 1);      // 16 x 32
    const dim3 gSq (E / BN, E  / BM, BATCH);  // 16 x 16 x 2

    // 1) Projections. Q,K: hi/lo compensated (softmax-sensitive). V: plain bf16.
    hipLaunchKernelGGL((gemm_mfma<0,0,2>), gBig, blk, 0, stream,
                       x, Wq, Q,  E, E, E, E, 0LL, 0LL, 0LL, 1.0f);
    hipLaunchKernelGGL((gemm_mfma<0,0,2>), gBig, blk, 0, stream,
                       x, Wk, Km, E, E, E, E, 0LL, 0LL, 0LL, 1.0f);
    hipLaunchKernelGGL((gemm_mfma<0,0,1>), gBig, blk, 0, stream,
                       x, Wv, V,  E, E, E, E, 0LL, 0LL, 0LL, 1.0f);

    // 2) S_b[e,f] = (1/8) * sum_s Q_b[s,e] K_b[s,f]   (A transposed; hi/lo)
    hipLaunchKernelGGL((gemm_mfma<1,0,2>), gSq, blk, 0, stream,
                       Q, Km, S, SEQ, E, E, E, BMAT, BMAT, BMAT, 0.125f);

    // 3) softmax over f, in place (4096 rows of 2048)
    hipLaunchKernelGGL(softmax_rows, dim3(BATCH * E), blk, 0, stream, S);

    // 4) AO_b[s,e] = sum_f V_b[s,f] * A_b[e,f]   (B transposed) -> into Q buffer
    hipLaunchKernelGGL((gemm_mfma<0,1,1>), gSq, blk, 0, stream,
                       V, S, Q, E, E, E, E, BMAT, BMAT, BMAT, 1.0f);

    // 5) out = AO @ Wo
    hipLaunchKernelGGL((gemm_mfma<0,0,1>), gBig, blk, 0, stream,
                       Q, Wo, out, E, E, E, E, 0LL, 0LL, 0LL, 1.0f);
}

// Round 12
// 412.294 us; speedup vs baseline: 1.9244x; 1.9244x over previous
//
#include <hip/hip_runtime.h>
#include <cstddef>
#include <cstdint>

// SelfAttention_71571335020783 on MI355X (gfx950) — fp16 MFMA pipeline
constexpr int E     = 2048;
constexpr int SEQ   = 2048;
constexpr int BATCH = 2;
constexpr int BS    = BATCH * SEQ;   // 4096

constexpr int BM = 128, BN = 128, BK = 64;

typedef _Float16 f16;
typedef f16  f16x4 __attribute__((ext_vector_type(4)));
typedef f16  f16x8 __attribute__((ext_vector_type(8)));
typedef float f32x4 __attribute__((ext_vector_type(4)));

// Direct global->LDS DMA, 16B per lane. LDS dest must be wave-uniform base
// (HW adds lane*16). Swizzle is applied on the GLOBAL source address and
// mirrored on the ds_read side (both-sides rule).
#define GLOAD16(g, l)                                                   \
    __builtin_amdgcn_global_load_lds(                                   \
        (const __attribute__((address_space(1))) void*)(g),             \
        (__attribute__((address_space(3))) void*)(l), 16, 0, 0)

// ---------------------------------------------------------------------------
// GEMM: C[m,n] = alpha * sum_k A[m,k] * B[n,k]   (both operands k-contiguous,
// row-major with leading dims lda/ldb). 128x128 tile, BK=64, 4 waves,
// 4x4 fragments of v_mfma_f32_16x16x32_f16 per wave.
//
// LDS tile layout: [row][8 chunks of 8 f16], chunk index XOR'd with (row&7).
// Staged via global_load_lds with pre-swizzled source; ds_read_b128 applies
// the same XOR -> uniform 8-lanes-per-bank-quad (the b128 floor).
//
// EPI 0: C row-major [m][n] (+ blockIdx.z * sC), CT = f16 or float.
// EPI 1: transposed per-batch fp16: C[b*2048^2 + n*2048 + (m&2047)], b=m>>11.
// ---------------------------------------------------------------------------
template <int EPI, typename CT>
__global__ __launch_bounds__(256) void gemm_f16(
    const f16* __restrict__ A, const f16* __restrict__ B, CT* __restrict__ C,
    int K, int lda, int ldb, int ldc,
    long long sA, long long sB, long long sC, float alpha)
{
    alignas(16) __shared__ f16 At[BM * BK];   // 16 KB
    alignas(16) __shared__ f16 Bt[BN * BK];   // 16 KB

    const int tid = threadIdx.x;
    const int l   = tid & 63;
    const int w   = tid >> 6;

    // XCD-aware swizzle of the flattened (x,y) block index (nwg % 8 == 0 here).
    const int nwg  = gridDim.x * gridDim.y;
    const int flat = blockIdx.y * gridDim.x + blockIdx.x;
    const int cpx  = nwg >> 3;
    const int swz  = (flat & 7) * cpx + (flat >> 3);
    const int bx = swz % gridDim.x, by = swz / gridDim.x;
    const int m0 = by * BM, n0 = bx * BN;

    const f16* Ab = A + (size_t)blockIdx.z * sA;
    const f16* Bb = B + (size_t)blockIdx.z * sB;

    const int lr = l & 15;        // fragment row/col within 16
    const int hi = l >> 4;        // k-group 0..3
    const int wm = (w >> 1) * 64; // wave tile offsets
    const int wn = (w & 1) * 64;

    f32x4 acc[4][4] = {};

    for (int k0 = 0; k0 < K; k0 += BK) {
        // ---- stage A,B tiles: 4 calls each, thread t covers chunk p*256+t ----
#pragma unroll
        for (int p = 0; p < 4; ++p) {
            const int ci  = p * 256 + tid;
            const int row = ci >> 3;
            const int sc  = (ci & 7) ^ (row & 7);     // pre-swizzled source chunk
            GLOAD16(Ab + (size_t)(m0 + row) * lda + k0 + sc * 8,
                    At + p * 2048 + w * 512);
            GLOAD16(Bb + (size_t)(n0 + row) * ldb + k0 + sc * 8,
                    Bt + p * 2048 + w * 512);
        }
        __syncthreads();

        f16x8 af[4][2], bf[4][2];
#pragma unroll
        for (int i = 0; i < 4; ++i)
#pragma unroll
            for (int ks = 0; ks < 2; ++ks) {
                const int ar = wm + i * 16 + lr;
                const int ap = (ks * 4 + hi) ^ (ar & 7);
                af[i][ks] = *reinterpret_cast<const f16x8*>(At + ar * 64 + ap * 8);
                const int br = wn + i * 16 + lr;
                const int bp = (ks * 4 + hi) ^ (br & 7);
                bf[i][ks] = *reinterpret_cast<const f16x8*>(Bt + br * 64 + bp * 8);
            }
#pragma unroll
        for (int ks = 0; ks < 2; ++ks)
#pragma unroll
            for (int i = 0; i < 4; ++i)
#pragma unroll
                for (int j = 0; j < 4; ++j)
                    acc[i][j] = __builtin_amdgcn_mfma_f32_16x16x32_f16(
                        af[i][ks], bf[j][ks], acc[i][j], 0, 0, 0);
        __syncthreads();
    }

    // Epilogue. C/D layout (HW-verified): col = lane&15, row = (lane>>4)*4 + r.
    if (EPI == 0) {
        CT* Cb = C + (size_t)blockIdx.z * sC;
#pragma unroll
        for (int i = 0; i < 4; ++i)
#pragma unroll
            for (int r = 0; r < 4; ++r) {
                const int row = m0 + wm + i * 16 + hi * 4 + r;
#pragma unroll
                for (int j = 0; j < 4; ++j) {
                    const int col = n0 + wn + j * 16 + lr;
                    Cb[(size_t)row * ldc + col] = (CT)(alpha * acc[i][j][r]);
                }
            }
    } else {
        // fp16 transposed per-batch write: 4 contiguous m-elements per store.
        f16* Cb = (f16*)C;
#pragma unroll
        for (int i = 0; i < 4; ++i) {
            const int rowb = m0 + wm + i * 16 + hi * 4;
            const long long base = ((long long)(rowb >> 11) << 22) + (rowb & 2047);
#pragma unroll
            for (int j = 0; j < 4; ++j) {
                const int col = n0 + wn + j * 16 + lr;
                f16x4 v = {(f16)(alpha * acc[i][j][0]), (f16)(alpha * acc[i][j][1]),
                           (f16)(alpha * acc[i][j][2]), (f16)(alpha * acc[i][j][3])};
                *reinterpret_cast<f16x4*>(Cb + base + (long long)col * 2048) = v;
            }
        }
    }
}

// ---------------------------------------------------------------------------
// fp32 -> fp16 elementwise (x)
// ---------------------------------------------------------------------------
__global__ __launch_bounds__(256) void conv_x_f16(
    const float* __restrict__ x, f16* __restrict__ xc, int n4)
{
    int i = blockIdx.x * 256 + threadIdx.x;
    const int stride = gridDim.x * 256;
    for (; i < n4; i += stride) {
        const float4 v = reinterpret_cast<const float4*>(x)[i];
        f16x4 h = {(f16)v.x, (f16)v.y, (f16)v.z, (f16)v.w};
        reinterpret_cast<f16x4*>(xc)[i] = h;
    }
}

// ---------------------------------------------------------------------------
// fp32 [2048][2048] -> fp16 transposed, 4 weights via blockIdx.z.
// 64x64 tiles through LDS.
// ---------------------------------------------------------------------------
__global__ __launch_bounds__(256) void conv_wT(
    const float* __restrict__ W0, const float* __restrict__ W1,
    const float* __restrict__ W2, const float* __restrict__ W3,
    f16* __restrict__ O0, f16* __restrict__ O1,
    f16* __restrict__ O2, f16* __restrict__ O3)
{
    const float* src; f16* dst;
    switch (blockIdx.z) {
        case 0: src = W0; dst = O0; break;
        case 1: src = W1; dst = O1; break;
        case 2: src = W2; dst = O2; break;
        default: src = W3; dst = O3; break;
    }
    __shared__ f16 t[64][68];               // [f][e], padded row
    const int e0 = blockIdx.y * 64, f0 = blockIdx.x * 64;
    const int tid = threadIdx.x;
    const int tf = (tid & 15) * 4;          // f within tile (float4)
    const int te = tid >> 4;                // e within tile (16 per pass)
#pragma unroll
    for (int p = 0; p < 4; ++p) {
        const int e = te + p * 16;
        const float4 v = *reinterpret_cast<const float4*>(
            &src[(size_t)(e0 + e) * 2048 + f0 + tf]);
        t[tf + 0][e] = (f16)v.x; t[tf + 1][e] = (f16)v.y;
        t[tf + 2][e] = (f16)v.z; t[tf + 3][e] = (f16)v.w;
    }
    __syncthreads();
#pragma unroll
    for (int p = 0; p < 4; ++p) {
        const int f = (tid >> 4) + p * 16;
        const int e = (tid & 15) * 4;
        const f16x4 v = *reinterpret_cast<const f16x4*>(&t[f][e]);
        *reinterpret_cast<f16x4*>(&dst[(size_t)(f0 + f) * 2048 + e0 + e]) = v;
    }
}

// ---------------------------------------------------------------------------
// Row softmax: fp32 S row (2048) -> fp16 A row. One 256-thread block per row.
// ---------------------------------------------------------------------------
__global__ __launch_bounds__(256) void softmax_rows_f16(
    const float* __restrict__ S, f16* __restrict__ A)
{
    const float* row = S + (size_t)blockIdx.x * 2048;
    f16* arow = A + (size_t)blockIdx.x * 2048;
    const int tid = threadIdx.x;

    float4 v0 = reinterpret_cast<const float4*>(row)[tid];
    float4 v1 = reinterpret_cast<const float4*>(row)[tid + 256];

    float m = fmaxf(fmaxf(fmaxf(v0.x, v0.y), fmaxf(v0.z, v0.w)),
                    fmaxf(fmaxf(v1.x, v1.y), fmaxf(v1.z, v1.w)));
#pragma unroll
    for (int off = 32; off > 0; off >>= 1) m = fmaxf(m, __shfl_xor(m, off));

    __shared__ float red[8];
    if ((tid & 63) == 0) red[tid >> 6] = m;
    __syncthreads();
    m = fmaxf(fmaxf(red[0], red[1]), fmaxf(red[2], red[3]));

    v0.x = __expf(v0.x - m); v0.y = __expf(v0.y - m);
    v0.z = __expf(v0.z - m); v0.w = __expf(v0.w - m);
    v1.x = __expf(v1.x - m); v1.y = __expf(v1.y - m);
    v1.z = __expf(v1.z - m); v1.w = __expf(v1.w - m);

    float s = v0.x + v0.y + v0.z + v0.w + v1.x + v1.y + v1.z + v1.w;
#pragma unroll
    for (int off = 32; off > 0; off >>= 1) s += __shfl_xor(s, off);
    if ((tid & 63) == 0) red[4 + (tid >> 6)] = s;
    __syncthreads();
    s = red[4] + red[5] + red[6] + red[7];

    const float inv = 1.0f / s;
    f16x4 a0 = {(f16)(v0.x * inv), (f16)(v0.y * inv), (f16)(v0.z * inv), (f16)(v0.w * inv)};
    f16x4 a1 = {(f16)(v1.x * inv), (f16)(v1.y * inv), (f16)(v1.z * inv), (f16)(v1.w * inv)};
    reinterpret_cast<f16x4*>(arow)[tid]       = a0;
    reinterpret_cast<f16x4*>(arow)[tid + 256] = a1;
}

// ---------------------------------------------------------------------------
extern "C" void kernel_launch(void* const* d_in, const int* in_sizes, int n_in,
                              void* d_out, int out_size, void* d_ws, size_t ws_size,
                              hipStream_t stream)
{
    const float* x  = (const float*)d_in[0];  // [2,2048,2048] == [4096,2048]
    const float* Wq = (const float*)d_in[1];
    const float* Wk = (const float*)d_in[2];
    const float* Wv = (const float*)d_in[3];
    const float* Wo = (const float*)d_in[4];
    float* out = (float*)d_out;               // [4096,2048] fp32

    // Workspace (134.2 MB total, same footprint as the passing round):
    // xc | WqT WkT WvT WoT | QT | KT | V | S(fp32)
    // A reuses QT (dead after S-GEMM); AO reuses KT (dead after S-GEMM).
    f16* ws16 = (f16*)d_ws;
    const size_t MATE = (size_t)BS * E;       // 8,388,608
    const size_t WMAT = (size_t)E * E;        // 4,194,304
    f16* xc  = ws16;
    f16* WqT = xc  + MATE;
    f16* WkT = WqT + WMAT;
    f16* WvT = WkT + WMAT;
    f16* WoT = WvT + WMAT;
    f16* QT  = WoT + WMAT;                    // [2][2048 f][2048 s]
    f16* KT  = QT  + MATE;
    f16* V   = KT  + MATE;                    // [4096 s][2048 f]
    float* S = (float*)(V + MATE);            // [2][2048 e][2048 f]
    f16* A   = QT;                            // reuse
    f16* AO  = KT;                            // reuse

    const dim3 blk(256);
    const long long BMATL = (long long)E * E;

    // 0) converters
    hipLaunchKernelGGL(conv_x_f16, dim3(2048), blk, 0, stream, x, xc, (int)(MATE / 4));
    hipLaunchKernelGGL(conv_wT, dim3(32, 32, 4), blk, 0, stream,
                       Wq, Wk, Wv, Wo, WqT, WkT, WvT, WoT);

    const dim3 gBig(E / BN, BS / BM, 1);      // 16 x 32
    const dim3 gSq (E / BN, E  / BM, BATCH);  // 16 x 16 x 2

    // 1) Q^T, K^T (transposed epilogue), V (row-major)
    hipLaunchKernelGGL((gemm_f16<1, f16>), gBig, blk, 0, stream,
                       xc, WqT, QT, E, E, E, E, 0LL, 0LL, 0LL, 1.0f);
    hipLaunchKernelGGL((gemm_f16<1, f16>), gBig, blk, 0, stream,
                       xc, WkT, KT, E, E, E, E, 0LL, 0LL, 0LL, 1.0f);
    hipLaunchKernelGGL((gemm_f16<0, f16>), gBig, blk, 0, stream,
                       xc, WvT, V, E, E, E, E, 0LL, 0LL, 0LL, 1.0f);

    // 2) S_b[e,f] = (1/8) * sum_s QT_b[e,s] KT_b[f,s]  -> fp32
    hipLaunchKernelGGL((gemm_f16<0, float>), gSq, blk, 0, stream,
                       QT, KT, S, SEQ, E, E, E, BMATL, BMATL, BMATL, 0.125f);

    // 3) softmax rows -> fp16 A
    hipLaunchKernelGGL(softmax_rows_f16, dim3(BATCH * E), blk, 0, stream, S, A);

    // 4) AO_b[s,e] = sum_f V_b[s,f] A_b[e,f]  -> fp16
    hipLaunchKernelGGL((gemm_f16<0, f16>), gSq, blk, 0, stream,
                       V, A, AO, E, E, E, E, BMATL, BMATL, BMATL, 1.0f);

    // 5) out = AO @ Wo  (B = WoT, k-contiguous) -> fp32
    hipLaunchKernelGGL((gemm_f16<0, float>), gBig, blk, 0, stream,
                       AO, WoT, out, E, E, E, E, 0LL, 0LL, 0LL, 1.0f);
}

// Round 13
// 389.621 us; speedup vs baseline: 2.0364x; 1.0582x over previous
//
#include <hip/hip_runtime.h>
#include <cstddef>
#include <cstdint>

// SelfAttention_71571335020783 on MI355X (gfx950) — fp16 MFMA, 2-phase dbuf
constexpr int E     = 2048;
constexpr int SEQ   = 2048;
constexpr int BATCH = 2;
constexpr int BS    = BATCH * SEQ;   // 4096

constexpr int BM = 128, BN = 128, BK = 64;

typedef _Float16 f16;
typedef f16  f16x4 __attribute__((ext_vector_type(4)));
typedef f16  f16x8 __attribute__((ext_vector_type(8)));
typedef float f32x4 __attribute__((ext_vector_type(4)));

#define GLOAD16(g, l)                                                   \
    __builtin_amdgcn_global_load_lds(                                   \
        (const __attribute__((address_space(1))) void*)(g),             \
        (__attribute__((address_space(3))) void*)(l), 16, 0, 0)

// ---------------------------------------------------------------------------
// Double-buffered K-loop core: acc += A[m0..+128, :K] * B[n0..+128, :K]^T.
// Both operands k-contiguous (row-major, leading dims lda/ldb).
// LDS: [2 bufs][row][8 chunks of 8 f16], chunk ^= (row&7); staged via
// global_load_lds with pre-swizzled SOURCE, read with the same XOR.
// ONE barrier per K-step: STAGE(t+1) issued BEFORE compute(t); the barrier's
// implicit vmcnt(0) drain lands after ds_read+MFMA, hiding HBM latency.
// ---------------------------------------------------------------------------
__device__ __forceinline__ void gemm_core(
    const f16* __restrict__ Ab, const f16* __restrict__ Bb,
    int K, int lda, int ldb, int m0, int n0,
    f16* At, f16* Bt, f32x4 acc[4][4])
{
    const int tid = threadIdx.x;
    const int l  = tid & 63;
    const int w  = tid >> 6;
    const int lr = l & 15;
    const int hi = l >> 4;
    const int wm = (w >> 1) * 64;
    const int wn = (w & 1) * 64;

    auto stage = [&](int buf, int k0) {
#pragma unroll
        for (int p = 0; p < 4; ++p) {
            const int ci  = p * 256 + tid;
            const int row = ci >> 3;
            const int sc  = (ci & 7) ^ (row & 7);     // pre-swizzled source chunk
            GLOAD16(Ab + (size_t)(m0 + row) * lda + k0 + sc * 8,
                    At + buf * (BM * BK) + p * 2048 + w * 512);
            GLOAD16(Bb + (size_t)(n0 + row) * ldb + k0 + sc * 8,
                    Bt + buf * (BN * BK) + p * 2048 + w * 512);
        }
    };

    stage(0, 0);
    __syncthreads();                      // drain prologue loads

    const int NT = K / BK;
    int cur = 0;
    for (int t = 0; t < NT; ++t) {
        if (t + 1 < NT) stage(cur ^ 1, (t + 1) * BK);   // prefetch next tile

        const f16* Ac = At + cur * (BM * BK);
        const f16* Bc = Bt + cur * (BN * BK);
        f16x8 af[4][2], bf[4][2];
#pragma unroll
        for (int i = 0; i < 4; ++i)
#pragma unroll
            for (int ks = 0; ks < 2; ++ks) {
                const int ar = wm + i * 16 + lr;
                const int ap = (ks * 4 + hi) ^ (ar & 7);
                af[i][ks] = *reinterpret_cast<const f16x8*>(Ac + ar * 64 + ap * 8);
                const int br = wn + i * 16 + lr;
                const int bp = (ks * 4 + hi) ^ (br & 7);
                bf[i][ks] = *reinterpret_cast<const f16x8*>(Bc + br * 64 + bp * 8);
            }
#pragma unroll
        for (int ks = 0; ks < 2; ++ks)
#pragma unroll
            for (int i = 0; i < 4; ++i)
#pragma unroll
                for (int j = 0; j < 4; ++j)
                    acc[i][j] = __builtin_amdgcn_mfma_f32_16x16x32_f16(
                        af[i][ks], bf[j][ks], acc[i][j], 0, 0, 0);

        __syncthreads();   // drains vmcnt(0)+lgkmcnt(0): next buf ready, this buf free
        cur ^= 1;
    }
}

__device__ __forceinline__ void swz_block(int gx, int gy, int& bx, int& by)
{
    const int nwg  = gx * gy;
    const int flat = blockIdx.y * gx + blockIdx.x;
    const int cpx  = nwg >> 3;                 // nwg % 8 == 0 for all our grids
    const int swz  = (flat & 7) * cpx + (flat >> 3);
    bx = swz % gx;
    by = swz / gx;
}

// ---------------------------------------------------------------------------
// Generic GEMM: C[m,n] = alpha * sum_k A[m,k]*B[n,k].  EPI 0: row-major CT.
// EPI 1: transposed per-batch fp16 C[b*2048^2 + n*2048 + (m&2047)].
// blockIdx.z = batch via sA/sB/sC strides.
// ---------------------------------------------------------------------------
template <int EPI, typename CT>
__global__ __launch_bounds__(256) void gemm_f16(
    const f16* __restrict__ A, const f16* __restrict__ B, CT* __restrict__ C,
    int K, int lda, int ldb, int ldc,
    long long sA, long long sB, long long sC, float alpha)
{
    alignas(16) __shared__ f16 At[2 * BM * BK];   // 32 KB
    alignas(16) __shared__ f16 Bt[2 * BN * BK];   // 32 KB

    int bx, by; swz_block(gridDim.x, gridDim.y, bx, by);
    const int m0 = by * BM, n0 = bx * BN;

    f32x4 acc[4][4] = {};
    gemm_core(A + (size_t)blockIdx.z * sA, B + (size_t)blockIdx.z * sB,
              K, lda, ldb, m0, n0, At, Bt, acc);

    const int l  = threadIdx.x & 63;
    const int w  = threadIdx.x >> 6;
    const int lr = l & 15, hi = l >> 4;
    const int wm = (w >> 1) * 64, wn = (w & 1) * 64;

    if (EPI == 0) {
        CT* Cb = C + (size_t)blockIdx.z * sC;
#pragma unroll
        for (int i = 0; i < 4; ++i)
#pragma unroll
            for (int r = 0; r < 4; ++r) {
                const int row = m0 + wm + i * 16 + hi * 4 + r;
#pragma unroll
                for (int j = 0; j < 4; ++j) {
                    const int col = n0 + wn + j * 16 + lr;
                    Cb[(size_t)row * ldc + col] = (CT)(alpha * acc[i][j][r]);
                }
            }
    } else {
        f16* Cb = (f16*)C;
#pragma unroll
        for (int i = 0; i < 4; ++i) {
            const int rowb = m0 + wm + i * 16 + hi * 4;
            const long long base = ((long long)(rowb >> 11) << 22) + (rowb & 2047);
#pragma unroll
            for (int j = 0; j < 4; ++j) {
                const int col = n0 + wn + j * 16 + lr;
                f16x4 v = {(f16)(alpha * acc[i][j][0]), (f16)(alpha * acc[i][j][1]),
                           (f16)(alpha * acc[i][j][2]), (f16)(alpha * acc[i][j][3])};
                *reinterpret_cast<f16x4*>(Cb + base + (long long)col * 2048) = v;
            }
        }
    }
}

// ---------------------------------------------------------------------------
// Merged QKV projection: grid (16, 32, 3). z=0 -> QT (transposed), z=1 -> KT
// (transposed), z=2 -> V (row-major). A = xc for all z (L2/L3 reuse).
// ---------------------------------------------------------------------------
__global__ __launch_bounds__(256) void qkv_f16(
    const f16* __restrict__ xc,
    const f16* __restrict__ WqT, const f16* __restrict__ WkT,
    const f16* __restrict__ WvT,
    f16* __restrict__ QT, f16* __restrict__ KT, f16* __restrict__ V)
{
    alignas(16) __shared__ f16 At[2 * BM * BK];
    alignas(16) __shared__ f16 Bt[2 * BN * BK];

    const int z = blockIdx.z;
    const f16* B = (z == 0) ? WqT : (z == 1) ? WkT : WvT;

    int bx, by; swz_block(gridDim.x, gridDim.y, bx, by);
    const int m0 = by * BM, n0 = bx * BN;

    f32x4 acc[4][4] = {};
    gemm_core(xc, B, E, E, E, m0, n0, At, Bt, acc);

    const int l  = threadIdx.x & 63;
    const int w  = threadIdx.x >> 6;
    const int lr = l & 15, hi = l >> 4;
    const int wm = (w >> 1) * 64, wn = (w & 1) * 64;

    if (z == 2) {
#pragma unroll
        for (int i = 0; i < 4; ++i)
#pragma unroll
            for (int r = 0; r < 4; ++r) {
                const int row = m0 + wm + i * 16 + hi * 4 + r;
#pragma unroll
                for (int j = 0; j < 4; ++j) {
                    const int col = n0 + wn + j * 16 + lr;
                    V[(size_t)row * E + col] = (f16)acc[i][j][r];
                }
            }
    } else {
        f16* Cb = (z == 0) ? QT : KT;
#pragma unroll
        for (int i = 0; i < 4; ++i) {
            const int rowb = m0 + wm + i * 16 + hi * 4;
            const long long base = ((long long)(rowb >> 11) << 22) + (rowb & 2047);
#pragma unroll
            for (int j = 0; j < 4; ++j) {
                const int col = n0 + wn + j * 16 + lr;
                f16x4 v = {(f16)acc[i][j][0], (f16)acc[i][j][1],
                           (f16)acc[i][j][2], (f16)acc[i][j][3]};
                *reinterpret_cast<f16x4*>(Cb + base + (long long)col * 2048) = v;
            }
        }
    }
}

// ---------------------------------------------------------------------------
__global__ __launch_bounds__(256) void conv_x_f16(
    const float* __restrict__ x, f16* __restrict__ xc, int n4)
{
    int i = blockIdx.x * 256 + threadIdx.x;
    const int stride = gridDim.x * 256;
    for (; i < n4; i += stride) {
        const float4 v = reinterpret_cast<const float4*>(x)[i];
        f16x4 h = {(f16)v.x, (f16)v.y, (f16)v.z, (f16)v.w};
        reinterpret_cast<f16x4*>(xc)[i] = h;
    }
}

__global__ __launch_bounds__(256) void conv_wT(
    const float* __restrict__ W0, const float* __restrict__ W1,
    const float* __restrict__ W2, const float* __restrict__ W3,
    f16* __restrict__ O0, f16* __restrict__ O1,
    f16* __restrict__ O2, f16* __restrict__ O3)
{
    const float* src; f16* dst;
    switch (blockIdx.z) {
        case 0: src = W0; dst = O0; break;
        case 1: src = W1; dst = O1; break;
        case 2: src = W2; dst = O2; break;
        default: src = W3; dst = O3; break;
    }
    __shared__ f16 t[64][68];
    const int e0 = blockIdx.y * 64, f0 = blockIdx.x * 64;
    const int tid = threadIdx.x;
    const int tf = (tid & 15) * 4;
    const int te = tid >> 4;
#pragma unroll
    for (int p = 0; p < 4; ++p) {
        const int e = te + p * 16;
        const float4 v = *reinterpret_cast<const float4*>(
            &src[(size_t)(e0 + e) * 2048 + f0 + tf]);
        t[tf + 0][e] = (f16)v.x; t[tf + 1][e] = (f16)v.y;
        t[tf + 2][e] = (f16)v.z; t[tf + 3][e] = (f16)v.w;
    }
    __syncthreads();
#pragma unroll
    for (int p = 0; p < 4; ++p) {
        const int f = (tid >> 4) + p * 16;
        const int e = (tid & 15) * 4;
        const f16x4 v = *reinterpret_cast<const f16x4*>(&t[f][e]);
        *reinterpret_cast<f16x4*>(&dst[(size_t)(f0 + f) * 2048 + e0 + e]) = v;
    }
}

__global__ __launch_bounds__(256) void softmax_rows_f16(
    const float* __restrict__ S, f16* __restrict__ A)
{
    const float* row = S + (size_t)blockIdx.x * 2048;
    f16* arow = A + (size_t)blockIdx.x * 2048;
    const int tid = threadIdx.x;

    float4 v0 = reinterpret_cast<const float4*>(row)[tid];
    float4 v1 = reinterpret_cast<const float4*>(row)[tid + 256];

    float m = fmaxf(fmaxf(fmaxf(v0.x, v0.y), fmaxf(v0.z, v0.w)),
                    fmaxf(fmaxf(v1.x, v1.y), fmaxf(v1.z, v1.w)));
#pragma unroll
    for (int off = 32; off > 0; off >>= 1) m = fmaxf(m, __shfl_xor(m, off));

    __shared__ float red[8];
    if ((tid & 63) == 0) red[tid >> 6] = m;
    __syncthreads();
    m = fmaxf(fmaxf(red[0], red[1]), fmaxf(red[2], red[3]));

    v0.x = __expf(v0.x - m); v0.y = __expf(v0.y - m);
    v0.z = __expf(v0.z - m); v0.w = __expf(v0.w - m);
    v1.x = __expf(v1.x - m); v1.y = __expf(v1.y - m);
    v1.z = __expf(v1.z - m); v1.w = __expf(v1.w - m);

    float s = v0.x + v0.y + v0.z + v0.w + v1.x + v1.y + v1.z + v1.w;
#pragma unroll
    for (int off = 32; off > 0; off >>= 1) s += __shfl_xor(s, off);
    if ((tid & 63) == 0) red[4 + (tid >> 6)] = s;
    __syncthreads();
    s = red[4] + red[5] + red[6] + red[7];

    const float inv = 1.0f / s;
    f16x4 a0 = {(f16)(v0.x * inv), (f16)(v0.y * inv), (f16)(v0.z * inv), (f16)(v0.w * inv)};
    f16x4 a1 = {(f16)(v1.x * inv), (f16)(v1.y * inv), (f16)(v1.z * inv), (f16)(v1.w * inv)};
    reinterpret_cast<f16x4*>(arow)[tid]       = a0;
    reinterpret_cast<f16x4*>(arow)[tid + 256] = a1;
}

// ---------------------------------------------------------------------------
extern "C" void kernel_launch(void* const* d_in, const int* in_sizes, int n_in,
                              void* d_out, int out_size, void* d_ws, size_t ws_size,
                              hipStream_t stream)
{
    const float* x  = (const float*)d_in[0];  // [2,2048,2048] == [4096,2048]
    const float* Wq = (const float*)d_in[1];
    const float* Wk = (const float*)d_in[2];
    const float* Wv = (const float*)d_in[3];
    const float* Wo = (const float*)d_in[4];
    float* out = (float*)d_out;               // [4096,2048] fp32

    // ws: xc | WqT WkT WvT WoT | QT | KT | V | S(fp32).  A=QT, AO=KT reuse.
    f16* ws16 = (f16*)d_ws;
    const size_t MATE = (size_t)BS * E;       // 8,388,608
    const size_t WMAT = (size_t)E * E;        // 4,194,304
    f16* xc  = ws16;
    f16* WqT = xc  + MATE;
    f16* WkT = WqT + WMAT;
    f16* WvT = WkT + WMAT;
    f16* WoT = WvT + WMAT;
    f16* QT  = WoT + WMAT;                    // [2][2048 f][2048 s]
    f16* KT  = QT  + MATE;
    f16* V   = KT  + MATE;                    // [4096 s][2048 f]
    float* S = (float*)(V + MATE);            // [2][2048 e][2048 f]
    f16* A   = QT;                            // reuse
    f16* AO  = KT;                            // reuse

    const dim3 blk(256);
    const long long BMATL = (long long)E * E;

    // 0) converters
    hipLaunchKernelGGL(conv_x_f16, dim3(2048), blk, 0, stream, x, xc, (int)(MATE / 4));
    hipLaunchKernelGGL(conv_wT, dim3(32, 32, 4), blk, 0, stream,
                       Wq, Wk, Wv, Wo, WqT, WkT, WvT, WoT);

    const dim3 gBig(E / BN, BS / BM, 1);      // 16 x 32
    const dim3 gSq (E / BN, E  / BM, BATCH);  // 16 x 16 x 2

    // 1) merged QKV: z=0 QT, z=1 KT (transposed epi), z=2 V (row-major)
    hipLaunchKernelGGL(qkv_f16, dim3(E / BN, BS / BM, 3), blk, 0, stream,
                       xc, WqT, WkT, WvT, QT, KT, V);

    // 2) S_b[e,f] = (1/8) * sum_s QT_b[e,s] KT_b[f,s]  -> fp32
    hipLaunchKernelGGL((gemm_f16<0, float>), gSq, blk, 0, stream,
                       QT, KT, S, SEQ, E, E, E, BMATL, BMATL, BMATL, 0.125f);

    // 3) softmax rows -> fp16 A
    hipLaunchKernelGGL(softmax_rows_f16, dim3(BATCH * E), blk, 0, stream, S, A);

    // 4) AO_b[s,e] = sum_f V_b[s,f] A_b[e,f]  -> fp16
    hipLaunchKernelGGL((gemm_f16<0, f16>), gSq, blk, 0, stream,
                       V, A, AO, E, E, E, E, BMATL, BMATL, BMATL, 1.0f);

    // 5) out = AO @ Wo  (B = WoT, k-contiguous) -> fp32
    hipLaunchKernelGGL((gemm_f16<0, float>), gBig, blk, 0, stream,
                       AO, WoT, out, E, E, E, E, 0LL, 0LL, 0LL, 1.0f);
}